// Round 1
// 683.250 us; speedup vs baseline: 1.1070x; 1.1070x over previous
//
#include <hip/hip_runtime.h>

#define HIDDEN 3584
#define NH 28
#define NKV 4
#define HD 128
#define NREP 7
#define SEQ 2048
#define BATCH 2
#define MTOK (BATCH*SEQ)   // 4096
#define QKVN 4608          // 3584 + 512 + 512
#define SCALE2 0.12751744f // 128^-0.5 * log2(e), folded into Q at RoPE

typedef __bf16 bf16x8 __attribute__((ext_vector_type(8)));
typedef float  f32x4  __attribute__((ext_vector_type(4)));

__device__ __forceinline__ unsigned short f2bf(float f){
    unsigned u = __builtin_bit_cast(unsigned, f);
    unsigned r = u + 0x7FFFu + ((u >> 16) & 1u);   // RNE
    return (unsigned short)(r >> 16);
}
__device__ __forceinline__ float bf2f(unsigned short h){
    unsigned u = ((unsigned)h) << 16;
    return __builtin_bit_cast(float, u);
}

// async global->LDS, 16B per lane; lds dest = wave-uniform base + lane*16
__device__ __forceinline__ void gload_lds16(const void* g, void* l){
    __builtin_amdgcn_global_load_lds(
        (const __attribute__((address_space(1))) void*)g,
        (__attribute__((address_space(3))) void*)l, 16, 0, 0);
}

// ---------------- elementwise cast fp32 -> bf16 ----------------
__global__ void cast_f32_bf16(const float* __restrict__ x, unsigned short* __restrict__ y, int n4){
    int i = blockIdx.x * blockDim.x + threadIdx.x;
    if (i < n4){
        float4 v = ((const float4*)x)[i];
        ushort4 o; o.x=f2bf(v.x); o.y=f2bf(v.y); o.z=f2bf(v.z); o.w=f2bf(v.w);
        ((ushort4*)y)[i] = o;
    }
}

// ---------------- W [K][N] fp32 -> Wt [N][K] bf16 ----------------
__global__ void transpose_cast(const float* __restrict__ W, unsigned short* __restrict__ Wt,
                               int K, int N){
    __shared__ float t[32][33];
    int n0 = blockIdx.x * 32, k0 = blockIdx.y * 32;
    int tx = threadIdx.x, ty = threadIdx.y;      // (32,8)
    #pragma unroll
    for (int r = 0; r < 4; r++)
        t[ty + r*8][tx] = W[(size_t)(k0 + ty + r*8) * N + n0 + tx];
    __syncthreads();
    #pragma unroll
    for (int r = 0; r < 4; r++)
        Wt[(size_t)(n0 + ty + r*8) * K + k0 + tx] = f2bf(t[tx][ty + r*8]);
}

// ---------------- V columns of qkv [B*S][4608] -> vt [B*512][SEQ] bf16 ----------------
__global__ void transpose_v(const unsigned short* __restrict__ qkv, unsigned short* __restrict__ vt){
    __shared__ unsigned short t[32][33];
    int s0 = blockIdx.x * 32, c0 = blockIdx.y * 32, b = blockIdx.z;
    int tx = threadIdx.x, ty = threadIdx.y;      // (32,8)
    #pragma unroll
    for (int r = 0; r < 4; r++)
        t[ty + r*8][tx] = qkv[(size_t)(b*SEQ + s0 + ty + r*8) * QKVN + 4096 + c0 + tx];
    __syncthreads();
    #pragma unroll
    for (int r = 0; r < 4; r++)
        vt[(size_t)(b*NKV*HD + c0 + ty + r*8) * SEQ + s0 + tx] = t[tx][ty + r*8];
}

// ======================================================================
// 256x256 8-phase GEMM (plain-HIP port of the m201 template):
//   BM=BN=256, BK=64, 512 threads = 8 waves (2M x 4N), per-wave C = 128x64.
//   LDS 128 KiB dynamic: A[2][256][64] + B[2][256][64] bf16, subtile-major
//   [rg(16rows)][cg(32cols)][1024B] with st_16x32 XOR swizzle (bit5 ^= bit9).
//   global_load_lds writes linearly -> swizzle via inverse-permuted SOURCE
//   lane (lane&32 ? lane^2 : lane) + swizzled ds_read byte offset.
//   8 phases / 2 K-tiles per iter; counted vmcnt(4) at phases 4/8 only
//   (2 half-tiles stay in flight across barriers); vmcnt(0) only last iter.
//   Stage ledger (iter i, tiles t0=2i in buf0, t0+1 in buf1):
//     P1:A0(t0+1)->b1  P2:A1(t0+1)->b1  P3:B0(t0+2)->b0  P4:B1(t0+2)->b0
//     P5:A0(t0+2)->b0  P6:A1(t0+2)->b0  P7:B0(t0+3)->b1  P8:B1(t0+3)->b1
//   Each region's last read is >=1 phase (one barrier pair) before its re-stage.
// ======================================================================

#define RD_A(MH, BUF) { \
    _Pragma("unroll") for (int fr = 0; fr < 4; fr++) \
    _Pragma("unroll") for (int kh = 0; kh < 2; kh++) \
        af[fr][kh] = *(const bf16x8*)(smA + (BUF)*32768 + (wm*8 + (MH)*4 + fr)*2048 + kh*1024 + lsw); }

#define RD_B(DST, NHh, BUF) { \
    _Pragma("unroll") for (int fn = 0; fn < 2; fn++) \
    _Pragma("unroll") for (int kh = 0; kh < 2; kh++) \
        DST[fn][kh] = *(const bf16x8*)(smB + (BUF)*32768 + (wn*4 + (NHh)*2 + fn)*2048 + kh*1024 + lsw); }

#define MFMA_Q(MH, NHh, BF) { \
    _Pragma("unroll") for (int kh = 0; kh < 2; kh++) \
    _Pragma("unroll") for (int fr = 0; fr < 4; fr++) \
    _Pragma("unroll") for (int fn = 0; fn < 2; fn++) \
        acc[(MH)*4+fr][(NHh)*2+fn] = __builtin_amdgcn_mfma_f32_16x16x32_bf16( \
            af[fr][kh], BF[fn][kh], acc[(MH)*4+fr][(NHh)*2+fn], 0, 0, 0); }

#define STG_A(KT, H, BUF) { \
    const unsigned short* _s = Ag + (size_t)((H)*128 + w*16 + srow)*K + (KT)*64 + scol; \
    char* _d = smA + (BUF)*32768 + ((H)*8 + w)*2048; \
    gload_lds16(_s, _d); gload_lds16(_s + 32, _d + 1024); }

#define STG_B(KT, H, BUF) { \
    const unsigned short* _s = Bg + (size_t)((H)*128 + w*16 + srow)*K + (KT)*64 + scol; \
    char* _d = smB + (BUF)*32768 + ((H)*8 + w)*2048; \
    gload_lds16(_s, _d); gload_lds16(_s + 32, _d + 1024); }

// barrier -> drain LDS reads -> pin -> boost prio (MFMA cluster follows)
#define PH_MID() \
    asm volatile("" ::: "memory"); \
    __builtin_amdgcn_s_barrier(); \
    asm volatile("s_waitcnt lgkmcnt(0)" ::: "memory"); \
    __builtin_amdgcn_sched_barrier(0); \
    __builtin_amdgcn_s_setprio(1)

#define PH_END() \
    __builtin_amdgcn_s_setprio(0); \
    asm volatile("" ::: "memory"); \
    __builtin_amdgcn_s_barrier(); \
    asm volatile("" ::: "memory")

#define PH_END_VM(NN) \
    __builtin_amdgcn_s_setprio(0); \
    asm volatile("s_waitcnt vmcnt(" #NN ")" ::: "memory"); \
    __builtin_amdgcn_s_barrier(); \
    asm volatile("" ::: "memory")

template<int OUT_BF16>
__global__ __launch_bounds__(512, 2) void gemm256_bt(const unsigned short* __restrict__ A,
                                                     const unsigned short* __restrict__ Bt,
                                                     const float* __restrict__ bias,
                                                     const float* __restrict__ bias2,
                                                     const float* __restrict__ bias3,
                                                     int nb1, int nb2,
                                                     void* __restrict__ C, int M, int N, int K){
    extern __shared__ char smem[];
    char* smA = smem;            // 2 x 32 KiB
    char* smB = smem + 65536;    // 2 x 32 KiB

    const int tid = threadIdx.x;
    const int lane = tid & 63, w = tid >> 6;          // 8 waves
    const int wm = w >> 2, wn = w & 3;                // 2M x 4N
    const int quad = lane >> 4, l16 = lane & 15;
    const int bm = blockIdx.x, bn = blockIdx.y;

    // stage source-lane permutation (inverse of st_16x32 swizzle, rule #21)
    const int sl   = (lane & 32) ? (lane ^ 2) : lane;
    const int srow = sl >> 2;          // row within 16-row subtile
    const int scol = (sl & 3) * 8;     // col (elems) within 32-col group
    // swizzled per-lane ds_read byte offset within a 1024B subtile
    const int lsw  = l16*64 + ((quad*16) ^ ((l16 & 8) << 2));

    const unsigned short* Ag = A  + (size_t)(bm*256) * K;
    const unsigned short* Bg = Bt + (size_t)(bn*256) * K;

    f32x4 acc[8][4] = {};
    bf16x8 af[4][2], bf0[2][2], bf1[2][2];

    const int T = K >> 6;        // K-tiles (K % 128 == 0 for all our shapes)
    const int half = T >> 1;

    // prologue: tile0 (all 4 halves) -> buf0 ; tile1 B-halves -> buf1
    STG_A(0, 0, 0); STG_A(0, 1, 0); STG_B(0, 0, 0); STG_B(0, 1, 0);
    STG_B(1, 0, 1); STG_B(1, 1, 1);
    asm volatile("s_waitcnt vmcnt(4)" ::: "memory");   // tile0 landed; tile1-B in flight
    __builtin_amdgcn_s_barrier();
    asm volatile("" ::: "memory");

    for (int i = 0; i < half; ++i){
        const int t0 = 2*i;
        const bool pre = (i < half - 1);
        // ---- K-tile t0 from buf0 ----
        // P1
        RD_A(0, 0); RD_B(bf0, 0, 0);
        STG_A(t0+1, 0, 1);
        PH_MID(); MFMA_Q(0, 0, bf0); PH_END();
        // P2
        RD_B(bf1, 1, 0);
        STG_A(t0+1, 1, 1);
        PH_MID(); MFMA_Q(0, 1, bf1); PH_END();
        // P3
        RD_A(1, 0);
        if (pre) STG_B(t0+2, 0, 0);
        PH_MID(); MFMA_Q(1, 1, bf1); PH_END();
        // P4 (no reads; af=mh1 from P3, bf0 from P1)
        if (pre) STG_B(t0+2, 1, 0);
        PH_MID(); MFMA_Q(1, 0, bf0);
        if (pre) { PH_END_VM(4); } else { PH_END_VM(0); }   // tile t0+1 fully landed
        // ---- K-tile t0+1 from buf1 ----
        // P5
        RD_A(0, 1); RD_B(bf0, 0, 1);
        if (pre) STG_A(t0+2, 0, 0);
        PH_MID(); MFMA_Q(0, 0, bf0); PH_END();
        // P6
        RD_B(bf1, 1, 1);
        if (pre) STG_A(t0+2, 1, 0);
        PH_MID(); MFMA_Q(0, 1, bf1); PH_END();
        // P7
        RD_A(1, 1);
        if (pre) STG_B(t0+3, 0, 1);
        PH_MID(); MFMA_Q(1, 1, bf1); PH_END();
        // P8
        if (pre) STG_B(t0+3, 1, 1);
        PH_MID(); MFMA_Q(1, 0, bf0);
        if (pre) { PH_END_VM(4); }                           // tile t0+2 fully landed
        else     { __builtin_amdgcn_s_setprio(0); }          // last iter: nothing outstanding
    }

    // epilogue: C row = bm*256 + wm*128 + mf*16 + quad*4 + r, col = bn*256 + wn*64 + nf*16 + l16
    #pragma unroll
    for (int nf = 0; nf < 4; nf++){
        int col = bn*256 + wn*64 + nf*16 + l16;
        float bb = 0.f;
        if (bias){
            if (col < nb1)      bb = bias[col];
            else if (col < nb2) bb = bias2[col - nb1];
            else                bb = bias3[col - nb2];
        }
        #pragma unroll
        for (int mf = 0; mf < 8; mf++){
            int row0 = bm*256 + wm*128 + mf*16 + quad*4;
            #pragma unroll
            for (int r = 0; r < 4; r++){
                float v = acc[mf][nf][r] + bb;
                if (OUT_BF16) ((unsigned short*)C)[(size_t)(row0+r)*N + col] = f2bf(v);
                else          ((float*)C)[(size_t)(row0+r)*N + col] = v;
            }
        }
    }
}

// ---------------- RoPE in-place on bf16, generic row stride ----------------
__global__ void rope_kernel(unsigned short* __restrict__ x, const float* __restrict__ cosp,
                            const float* __restrict__ sinp, int nheads, int rowstride,
                            float outscale, int total){
    int i = blockIdx.x * blockDim.x + threadIdx.x;
    if (i >= total) return;
    int d   = i & 63;
    int h   = (i >> 6) % nheads;
    int row = i / (64 * nheads);
    int s   = row & (SEQ - 1);
    size_t base = (size_t)row * rowstride + h * HD;
    float x1 = bf2f(x[base + d]), x2 = bf2f(x[base + d + 64]);
    float c1 = cosp[s*HD + d],  c2 = cosp[s*HD + d + 64];
    float s1 = sinp[s*HD + d],  s2 = sinp[s*HD + d + 64];
    x[base + d]      = f2bf((x1 * c1 - x2 * s1) * outscale);
    x[base + d + 64] = f2bf((x2 * c2 + x1 * s2) * outscale);
}

// ---------------- MFMA flash attention, balanced + drain-free pipeline ----------------
// grid (8 pairs, 28 heads, 2 batch), 256 threads = 4 waves.
// Block p processes qt = 15-p then qt = p  -> exactly 34 K-iters per block.
// Ks[2]: double-buffered [kc8(16)][key(64)][8]; DMA(kt+1) issued at iter top,
// consumed next iter -> vmcnt(0) drain at barriers is fully covered by compute.
// Vs: single [kch(8)][d(128)][8]; DMA at iter top, read after b1 (~900cyc to land).
// Ps: [qrow(128)][64] bf16, XOR-swizzled (tn^quad on 16-col group) -> conflict-free.
__global__ __launch_bounds__(256, 2) void attn_mfma(const unsigned short* __restrict__ qkv,
                                                    const unsigned short* __restrict__ vt,
                                                    unsigned short* __restrict__ ao){
    __shared__ unsigned short Ks[2][16*64*8];
    __shared__ unsigned short Vs[8*128*8];
    __shared__ unsigned short Ps[128*64];
    const int h = blockIdx.y, b = blockIdx.z;
    const int g = h / NREP;
    const int tid = threadIdx.x;
    const int lane = tid & 63, w = tid >> 6;
    const int quad = lane >> 4, l16 = lane & 15;

    // DMA source bases (lane-fixed parts)
    const unsigned short* kdma  = qkv + (size_t)(b*SEQ + lane)*QKVN + 3584 + g*HD;
    const unsigned short* vdma0 = vt  + ((size_t)(b*NKV + g)*HD + lane)*SEQ;

    for (int ph = 0; ph < 2; ph++){
        const int qt = ph ? (int)blockIdx.x : (15 - (int)blockIdx.x);
        const int qrow0 = qt*128 + w*32;

        // Q fragments (A-layout, scale pre-folded by RoPE): lane holds Q[row=l16][d=kc*32+quad*8+j]
        bf16x8 qf[2][4];
        #pragma unroll
        for (int tm = 0; tm < 2; tm++){
            const unsigned short* qp = qkv + (size_t)(b*SEQ + qrow0 + tm*16 + l16)*QKVN + h*HD;
            #pragma unroll
            for (int kc = 0; kc < 4; kc++)
                qf[tm][kc] = *(const bf16x8*)&qp[kc*32 + quad*8];
        }

        f32x4 oacc[2][8];
        float m_i[2][4], l_i[2][4];
        #pragma unroll
        for (int tm = 0; tm < 2; tm++){
            #pragma unroll
            for (int tn = 0; tn < 8; tn++) oacc[tm][tn] = (f32x4){0.f, 0.f, 0.f, 0.f};
            #pragma unroll
            for (int r = 0; r < 4; r++){ m_i[tm][r] = -1e30f; l_i[tm][r] = 0.f; }
        }

        const int ktmax = 2*qt + 1;
        // prologue: DMA K(0) -> Ks[0]
        #pragma unroll
        for (int i = 0; i < 4; i++){
            int kc = w*4 + i;
            gload_lds16(kdma + kc*8, &Ks[0][kc*64*8]);
        }
        __syncthreads();   // drain K0 (once per phase)

        int cur = 0;
        for (int kt = 0; kt <= ktmax; kt++){
            // issue next-iteration K DMA into the other buffer (freed by prev b2)
            if (kt < ktmax){
                const unsigned short* kp = kdma + (size_t)((kt+1)*64)*QKVN;
                #pragma unroll
                for (int i = 0; i < 4; i++){
                    int kc = w*4 + i;
                    gload_lds16(kp + kc*8, &Ks[cur^1][kc*64*8]);
                }
            }
            // V DMA for this kt (Vs freed by prev b2; consumed after b1 below)
            #pragma unroll
            for (int i = 0; i < 4; i++){
                int e = w*4 + i, kch = e >> 1, half = e & 1;
                gload_lds16(vdma0 + (size_t)(half*64)*SEQ + kt*64 + kch*8,
                            &Vs[(kch*128 + half*64)*8]);
            }

            // S = Q K^T from Ks[cur] (DMA'd last iter, drained at prev barrier)
            f32x4 sacc[2][4];
            #pragma unroll
            for (int tm = 0; tm < 2; tm++)
                #pragma unroll
                for (int tn = 0; tn < 4; tn++) sacc[tm][tn] = (f32x4){0.f, 0.f, 0.f, 0.f};
            #pragma unroll
            for (int kc = 0; kc < 4; kc++){
                bf16x8 kf[4];
                #pragma unroll
                for (int tn = 0; tn < 4; tn++)
                    kf[tn] = *(const bf16x8*)&Ks[cur][((kc*4 + quad)*64 + tn*16 + l16)*8];
                #pragma unroll
                for (int tm = 0; tm < 2; tm++)
                    #pragma unroll
                    for (int tn = 0; tn < 4; tn++)
                        sacc[tm][tn] = __builtin_amdgcn_mfma_f32_16x16x32_bf16(qf[tm][kc], kf[tn], sacc[tm][tn], 0, 0, 0);
            }

            // online softmax (exp2 domain; scale pre-folded into Q)
            const int kbase = kt*64;
            const bool need_mask = (kbase + 63 > qrow0);   // wave-uniform
            #pragma unroll
            for (int tm = 0; tm < 2; tm++){
                #pragma unroll
                for (int r = 0; r < 4; r++){
                    float sv[4];
                    #pragma unroll
                    for (int tn = 0; tn < 4; tn++) sv[tn] = sacc[tm][tn][r];
                    if (need_mask){
                        int qrow = qrow0 + tm*16 + quad*4 + r;
                        #pragma unroll
                        for (int tn = 0; tn < 4; tn++)
                            if (kbase + tn*16 + l16 > qrow) sv[tn] = -1e9f;
                    }
                    float rm = fmaxf(fmaxf(sv[0], sv[1]), fmaxf(sv[2], sv[3]));
                    rm = fmaxf(rm, __shfl_xor(rm, 1));
                    rm = fmaxf(rm, __shfl_xor(rm, 2));
                    rm = fmaxf(rm, __shfl_xor(rm, 4));
                    rm = fmaxf(rm, __shfl_xor(rm, 8));
                    float newm = fmaxf(m_i[tm][r], rm);
                    float alpha = exp2f(m_i[tm][r] - newm);
                    m_i[tm][r] = newm;
                    float rs = 0.f;
                    int prow = (w*32 + tm*16 + quad*4 + r)*64;
                    #pragma unroll
                    for (int tn = 0; tn < 4; tn++){
                        float p = exp2f(sv[tn] - newm);
                        rs += p;
                        Ps[prow + ((tn ^ quad) << 4) + l16] = f2bf(p);
                    }
                    l_i[tm][r] = l_i[tm][r] * alpha + rs;   // lane-partial l (reduced at epilogue)
                    #pragma unroll
                    for (int tn = 0; tn < 8; tn++) oacc[tm][tn][r] *= alpha;
                }
            }
            __syncthreads();   // b1: V ready (DMA had QK^T+softmax to land), K(kt+1) drained early

            // O += P V : A-frags from swizzled Ps (wave-private rows), B-frags from Vs
            #pragma unroll
            for (int ks = 0; ks < 2; ks++){
                bf16x8 pf[2];
                #pragma unroll
                for (int tm = 0; tm < 2; tm++){
                    int prow = (w*32 + tm*16 + l16)*64;
                    int sw = (((2*ks + (quad >> 1)) ^ (l16 >> 2)) << 4) + (quad & 1)*8;
                    pf[tm] = *(const bf16x8*)&Ps[prow + sw];
                }
                #pragma unroll
                for (int tn = 0; tn < 8; tn++){
                    bf16x8 vf = *(const bf16x8*)&Vs[((ks*4 + quad)*128 + tn*16 + l16)*8];
                    #pragma unroll
                    for (int tm = 0; tm < 2; tm++)
                        oacc[tm][tn] = __builtin_amdgcn_mfma_f32_16x16x32_bf16(pf[tm], vf, oacc[tm][tn], 0, 0, 0);
                }
            }
            __syncthreads();   // b2: frees Vs & Ks[cur]; nothing outstanding -> no drain
            cur ^= 1;
        }

        // epilogue: reduce lane-partial l across the row's 16 lanes, write ao
        #pragma unroll
        for (int tm = 0; tm < 2; tm++){
            #pragma unroll
            for (int r = 0; r < 4; r++){
                float lt = l_i[tm][r];
                lt += __shfl_xor(lt, 1);
                lt += __shfl_xor(lt, 2);
                lt += __shfl_xor(lt, 4);
                lt += __shfl_xor(lt, 8);
                float inv = 1.f / lt;
                size_t base = ((size_t)(b*SEQ + qrow0 + tm*16 + quad*4 + r)) * (NH*HD) + h*HD;
                #pragma unroll
                for (int tn = 0; tn < 8; tn++)
                    ao[base + tn*16 + l16] = f2bf(oacc[tm][tn][r] * inv);
            }
        }
    }
}

extern "C" void kernel_launch(void* const* d_in, const int* in_sizes, int n_in,
                              void* d_out, int out_size, void* d_ws, size_t ws_size,
                              hipStream_t stream){
    const float* hs   = (const float*)d_in[0];
    const float* cosp = (const float*)d_in[1];
    const float* sinp = (const float*)d_in[2];
    const float* Wq   = (const float*)d_in[3];
    const float* bq   = (const float*)d_in[4];
    const float* Wk   = (const float*)d_in[5];
    const float* bk   = (const float*)d_in[6];
    const float* Wv   = (const float*)d_in[7];
    const float* bv   = (const float*)d_in[8];
    const float* Wo   = (const float*)d_in[9];
    float* out = (float*)d_out;
    char* ws = (char*)d_ws;

    // one-time: allow 128 KiB dynamic LDS on the 256^2 GEMM
    static bool once = [](){
        hipFuncSetAttribute(reinterpret_cast<const void*>(gemm256_bt<1>),
                            hipFuncAttributeMaxDynamicSharedMemorySize, 131072);
        hipFuncSetAttribute(reinterpret_cast<const void*>(gemm256_bt<0>),
                            hipFuncAttributeMaxDynamicSharedMemorySize, 131072);
        return true;
    }();
    (void)once;

    // workspace layout (bytes)
    unsigned short* hsb  = (unsigned short*)(ws + 0);          // 4096x3584 bf16 = 29,360,128
    unsigned short* Wqt  = (unsigned short*)(ws + 29360128);   // 3584x3584 bf16 (Wq^T)
    unsigned short* Wkt  = (unsigned short*)(ws + 55050240);   //  512x3584 bf16 (contiguous after Wqt)
    unsigned short* Wvt  = (unsigned short*)(ws + 58720256);   //  512x3584 bf16 (contiguous after Wkt)
    unsigned short* qkvb = (unsigned short*)(ws + 62390272);   // 4096x4608 bf16 = 37,748,736
    unsigned short* ao   = hsb;                                // reuse: hsb consumed by QKV gemm
    unsigned short* Wot  = Wqt;                                // reuse: W^T block consumed by QKV gemm
    unsigned short* vtb  = (unsigned short*)(ws + 55050240);   // reuse Wkt/Wvt: 2x512x2048 bf16

    int n4 = MTOK * HIDDEN / 4;
    cast_f32_bf16<<<(n4 + 255) / 256, 256, 0, stream>>>(hs, hsb, n4);
    transpose_cast<<<dim3(112, 112), dim3(32, 8), 0, stream>>>(Wq, Wqt, HIDDEN, NH*HD);
    transpose_cast<<<dim3(16, 112),  dim3(32, 8), 0, stream>>>(Wk, Wkt, HIDDEN, NKV*HD);
    transpose_cast<<<dim3(16, 112),  dim3(32, 8), 0, stream>>>(Wv, Wvt, HIDDEN, NKV*HD);

    // fused QKV projection: Bt = [Wqt;Wkt;Wvt] (contiguous), N = 4608, 256^2 tiles
    gemm256_bt<1><<<dim3(16, 18), 512, 131072, stream>>>(hsb, Wqt, bq, bk, bv, 3584, 4096,
                                                         qkvb, MTOK, QKVN, HIDDEN);

    // RoPE: q gets softmax scale*log2(e) folded in; k plain
    rope_kernel<<<(MTOK*NH*64  + 255) / 256, 256, 0, stream>>>(qkvb,        cosp, sinp, NH,  QKVN, SCALE2, MTOK*NH*64);
    rope_kernel<<<(MTOK*NKV*64 + 255) / 256, 256, 0, stream>>>(qkvb + 3584, cosp, sinp, NKV, QKVN, 1.0f,   MTOK*NKV*64);

    // V columns -> vt (overwrites Wkt/Wvt region; QKV gemm already done)
    transpose_v<<<dim3(64, 16, 2), dim3(32, 8), 0, stream>>>(qkvb, vtb);

    transpose_cast<<<dim3(112, 112), dim3(32, 8), 0, stream>>>(Wo, Wot, NH*HD, HIDDEN);

    attn_mfma<<<dim3(8, 28, 2), 256, 0, stream>>>(qkvb, vtb, ao);

    gemm256_bt<0><<<dim3(16, 14), 512, 131072, stream>>>(ao, Wot, nullptr, nullptr, nullptr, 1<<30, 1<<30,
                                                         out, MTOK, HIDDEN, NH*HD);
}

// Round 3
// 661.449 us; speedup vs baseline: 1.1435x; 1.0330x over previous
//
#include <hip/hip_runtime.h>

#define HIDDEN 3584
#define NH 28
#define NKV 4
#define HD 128
#define NREP 7
#define SEQ 2048
#define BATCH 2
#define MTOK (BATCH*SEQ)   // 4096
#define QKVN 4608          // 3584 + 512 + 512
#define SCALE2 0.12751744f // 128^-0.5 * log2(e), folded into Q at RoPE

typedef __bf16 bf16x8 __attribute__((ext_vector_type(8)));
typedef float  f32x4  __attribute__((ext_vector_type(4)));

__device__ __forceinline__ unsigned short f2bf(float f){
    unsigned u = __builtin_bit_cast(unsigned, f);
    unsigned r = u + 0x7FFFu + ((u >> 16) & 1u);   // RNE
    return (unsigned short)(r >> 16);
}
__device__ __forceinline__ float bf2f(unsigned short h){
    unsigned u = ((unsigned)h) << 16;
    return __builtin_bit_cast(float, u);
}

// async global->LDS, 16B per lane; lds dest = wave-uniform base + lane*16
__device__ __forceinline__ void gload_lds16(const void* g, void* l){
    __builtin_amdgcn_global_load_lds(
        (const __attribute__((address_space(1))) void*)g,
        (__attribute__((address_space(3))) void*)l, 16, 0, 0);
}

// ---------------- elementwise cast fp32 -> bf16 ----------------
__global__ void cast_f32_bf16(const float* __restrict__ x, unsigned short* __restrict__ y, int n4){
    int i = blockIdx.x * blockDim.x + threadIdx.x;
    if (i < n4){
        float4 v = ((const float4*)x)[i];
        ushort4 o; o.x=f2bf(v.x); o.y=f2bf(v.y); o.z=f2bf(v.z); o.w=f2bf(v.w);
        ((ushort4*)y)[i] = o;
    }
}

// ---------------- W [K][N] fp32 -> Wt [N][K] bf16 ----------------
__global__ void transpose_cast(const float* __restrict__ W, unsigned short* __restrict__ Wt,
                               int K, int N){
    __shared__ float t[32][33];
    int n0 = blockIdx.x * 32, k0 = blockIdx.y * 32;
    int tx = threadIdx.x, ty = threadIdx.y;      // (32,8)
    #pragma unroll
    for (int r = 0; r < 4; r++)
        t[ty + r*8][tx] = W[(size_t)(k0 + ty + r*8) * N + n0 + tx];
    __syncthreads();
    #pragma unroll
    for (int r = 0; r < 4; r++)
        Wt[(size_t)(n0 + ty + r*8) * K + k0 + tx] = f2bf(t[tx][ty + r*8]);
}

// ---------------- V columns of qkv [B*S][4608] -> vt [B*512][SEQ] bf16 ----------------
__global__ void transpose_v(const unsigned short* __restrict__ qkv, unsigned short* __restrict__ vt){
    __shared__ unsigned short t[32][33];
    int s0 = blockIdx.x * 32, c0 = blockIdx.y * 32, b = blockIdx.z;
    int tx = threadIdx.x, ty = threadIdx.y;      // (32,8)
    #pragma unroll
    for (int r = 0; r < 4; r++)
        t[ty + r*8][tx] = qkv[(size_t)(b*SEQ + s0 + ty + r*8) * QKVN + 4096 + c0 + tx];
    __syncthreads();
    #pragma unroll
    for (int r = 0; r < 4; r++)
        vt[(size_t)(b*NKV*HD + c0 + ty + r*8) * SEQ + s0 + tx] = t[tx][ty + r*8];
}

// ======================================================================
// Shared pieces of the 8-phase GEMM family (m201-template port):
//   st_16x32 XOR swizzle; global_load_lds writes linearly -> swizzle via
//   inverse-permuted SOURCE lane (lane&32 ? lane^2 : lane) + swizzled
//   ds_read byte offset. Counted vmcnt (never 0 mid-loop).
// ======================================================================

#define STG_A(KT, H, BUF) { \
    const unsigned short* _s = Ag + (size_t)((H)*128 + w*16 + srow)*K + (KT)*64 + scol; \
    char* _d = smA + (BUF)*32768 + ((H)*8 + w)*2048; \
    gload_lds16(_s, _d); gload_lds16(_s + 32, _d + 1024); }

#define STG_B(KT, H, BUF) { \
    const unsigned short* _s = Bg + (size_t)((H)*128 + w*16 + srow)*K + (KT)*64 + scol; \
    char* _d = smB + (BUF)*32768 + ((H)*8 + w)*2048; \
    gload_lds16(_s, _d); gload_lds16(_s + 32, _d + 1024); }

// barrier -> drain LDS reads -> pin -> boost prio (MFMA cluster follows)
#define PH_MID() \
    asm volatile("" ::: "memory"); \
    __builtin_amdgcn_s_barrier(); \
    asm volatile("s_waitcnt lgkmcnt(0)" ::: "memory"); \
    __builtin_amdgcn_sched_barrier(0); \
    __builtin_amdgcn_s_setprio(1)

#define PH_END() \
    __builtin_amdgcn_s_setprio(0); \
    asm volatile("" ::: "memory"); \
    __builtin_amdgcn_s_barrier(); \
    asm volatile("" ::: "memory")

#define PH_END_VM(NN) \
    __builtin_amdgcn_s_setprio(0); \
    asm volatile("s_waitcnt vmcnt(" #NN ")" ::: "memory"); \
    __builtin_amdgcn_s_barrier(); \
    asm volatile("" ::: "memory")

// ======================================================================
// 256x256 8-phase GEMM: BM=BN=256, BK=64, 512 thr = 8 waves (2Mx4N),
// per-wave C = 128x64. LDS 128 KiB.
//   Stage ledger (iter i, tiles t0=2i in buf0, t0+1 in buf1):
//     P1:A0(t0+1)->b1  P2:A1(t0+1)->b1  P3:B0(t0+2)->b0  P4:B1(t0+2)->b0
//     P5:A0(t0+2)->b0  P6:A1(t0+2)->b0  P7:B0(t0+3)->b1  P8:B1(t0+3)->b1
//   vmcnt(4) at end-P4/P8 only; vmcnt(0) only last iteration.
// ======================================================================

#define RD_A(MH, BUF) { \
    _Pragma("unroll") for (int fr = 0; fr < 4; fr++) \
    _Pragma("unroll") for (int kh = 0; kh < 2; kh++) \
        af[fr][kh] = *(const bf16x8*)(smA + (BUF)*32768 + (wm*8 + (MH)*4 + fr)*2048 + kh*1024 + lsw); }

#define RD_B(DST, NHh, BUF) { \
    _Pragma("unroll") for (int fn = 0; fn < 2; fn++) \
    _Pragma("unroll") for (int kh = 0; kh < 2; kh++) \
        DST[fn][kh] = *(const bf16x8*)(smB + (BUF)*32768 + (wn*4 + (NHh)*2 + fn)*2048 + kh*1024 + lsw); }

#define MFMA_Q(MH, NHh, BF) { \
    _Pragma("unroll") for (int kh = 0; kh < 2; kh++) \
    _Pragma("unroll") for (int fr = 0; fr < 4; fr++) \
    _Pragma("unroll") for (int fn = 0; fn < 2; fn++) \
        acc[(MH)*4+fr][(NHh)*2+fn] = __builtin_amdgcn_mfma_f32_16x16x32_bf16( \
            af[fr][kh], BF[fn][kh], acc[(MH)*4+fr][(NHh)*2+fn], 0, 0, 0); }

template<int OUT_BF16>
__global__ __launch_bounds__(512, 2) void gemm256_bt(const unsigned short* __restrict__ A,
                                                     const unsigned short* __restrict__ Bt,
                                                     const float* __restrict__ bias,
                                                     int nb1,
                                                     void* __restrict__ C, int ldc, int K){
    extern __shared__ char smem[];
    char* smA = smem;            // 2 x 32 KiB
    char* smB = smem + 65536;    // 2 x 32 KiB

    const int tid = threadIdx.x;
    const int lane = tid & 63, w = tid >> 6;          // 8 waves
    const int wm = w >> 2, wn = w & 3;                // 2M x 4N
    const int quad = lane >> 4, l16 = lane & 15;
    const int bm = blockIdx.x, bn = blockIdx.y;

    // stage source-lane permutation (inverse of st_16x32 swizzle, rule #21)
    const int sl   = (lane & 32) ? (lane ^ 2) : lane;
    const int srow = sl >> 2;          // row within 16-row subtile
    const int scol = (sl & 3) * 8;     // col (elems) within 32-col group
    // swizzled per-lane ds_read byte offset within a 1024B subtile
    const int lsw  = l16*64 + ((quad*16) ^ ((l16 & 8) << 2));

    const unsigned short* Ag = A  + (size_t)(bm*256) * K;
    const unsigned short* Bg = Bt + (size_t)(bn*256) * K;

    f32x4 acc[8][4] = {};
    bf16x8 af[4][2], bf0[2][2], bf1[2][2];

    const int T = K >> 6;        // K-tiles
    const int half = T >> 1;

    // prologue: tile0 (all 4 halves) -> buf0 ; tile1 B-halves -> buf1
    STG_A(0, 0, 0); STG_A(0, 1, 0); STG_B(0, 0, 0); STG_B(0, 1, 0);
    STG_B(1, 0, 1); STG_B(1, 1, 1);
    asm volatile("s_waitcnt vmcnt(4)" ::: "memory");   // tile0 landed; tile1-B in flight
    __builtin_amdgcn_s_barrier();
    asm volatile("" ::: "memory");

    for (int i = 0; i < half; ++i){
        const int t0 = 2*i;
        const bool pre = (i < half - 1);
        // ---- K-tile t0 from buf0 ----
        // P1
        RD_A(0, 0); RD_B(bf0, 0, 0);
        STG_A(t0+1, 0, 1);
        PH_MID(); MFMA_Q(0, 0, bf0); PH_END();
        // P2
        RD_B(bf1, 1, 0);
        STG_A(t0+1, 1, 1);
        PH_MID(); MFMA_Q(0, 1, bf1); PH_END();
        // P3
        RD_A(1, 0);
        if (pre) STG_B(t0+2, 0, 0);
        PH_MID(); MFMA_Q(1, 1, bf1); PH_END();
        // P4 (no reads; af=mh1 from P3, bf0 from P1)
        if (pre) STG_B(t0+2, 1, 0);
        PH_MID(); MFMA_Q(1, 0, bf0);
        if (pre) { PH_END_VM(4); } else { PH_END_VM(0); }   // tile t0+1 fully landed
        // ---- K-tile t0+1 from buf1 ----
        // P5
        RD_A(0, 1); RD_B(bf0, 0, 1);
        if (pre) STG_A(t0+2, 0, 0);
        PH_MID(); MFMA_Q(0, 0, bf0); PH_END();
        // P6
        RD_B(bf1, 1, 1);
        if (pre) STG_A(t0+2, 1, 0);
        PH_MID(); MFMA_Q(0, 1, bf1); PH_END();
        // P7
        RD_A(1, 1);
        if (pre) STG_B(t0+3, 0, 1);
        PH_MID(); MFMA_Q(1, 1, bf1); PH_END();
        // P8
        if (pre) STG_B(t0+3, 1, 1);
        PH_MID(); MFMA_Q(1, 0, bf0);
        if (pre) { PH_END_VM(4); }                           // tile t0+2 fully landed
        else     { __builtin_amdgcn_s_setprio(0); }          // last iter: nothing outstanding
    }

    // epilogue: nf innermost so the four 32B chunks of each 128B row-segment
    // are written back-to-back (write-combine; kills the RMW amplification)
    float bb[4];
    #pragma unroll
    for (int nf = 0; nf < 4; nf++){
        int col = bn*256 + wn*64 + nf*16 + l16;
        bb[nf] = (bias && col < nb1) ? bias[col] : 0.f;
    }
    const size_t cb = (size_t)(bn*256 + wn*64);
    #pragma unroll
    for (int mf = 0; mf < 8; mf++){
        int row0 = bm*256 + wm*128 + mf*16 + quad*4;
        #pragma unroll
        for (int r = 0; r < 4; r++){
            size_t rb = (size_t)(row0+r)*ldc + cb;
            #pragma unroll
            for (int nf = 0; nf < 4; nf++){
                float v = acc[mf][nf][r] + bb[nf];
                if (OUT_BF16) ((unsigned short*)C)[rb + nf*16 + l16] = f2bf(v);
                else          ((float*)C)[rb + nf*16 + l16] = v;
            }
        }
    }
}

// ======================================================================
// 256x128 4-phase GEMM (KV projection): BM=256, BN=128, BK=64,
// 512 thr = 8 waves (4M x 2N), per-wave C = 64x64. LDS 96 KiB
// (A 2x32K + B 2x16K). 4 phases / 2 K-tiles per iter.
//   Stage ledger (iter i, t0=2i in buf0, t0+1 in buf1):
//     P1: A(t0+1)->b1 (4gl)   P2: A(t0+2)+B(t0+2)->b0 (6gl)
//     P3: -                   P4: B(t0+3)->b1 (2gl)
//   Reads: P1 all frags of b0 (16 rds), P3 all frags of b1.
//   Waits: end-P2 vmcnt(6)  [drains prevP4-B + P1-A = tile t0+1]
//          end-P4 vmcnt(2)  [drains P2 = tile t0+2]
//   Region hazards: every write lands >=1 barrier after the region's
//   last ds_read was lgkmcnt(0)-drained (drain is pre-END-barrier).
// ======================================================================

#define RDKV_A(BUF) { \
    _Pragma("unroll") for (int fr = 0; fr < 4; fr++) \
    _Pragma("unroll") for (int kh = 0; kh < 2; kh++) \
        af[fr][kh] = *(const bf16x8*)(smA + (BUF)*32768 + (wm*4 + fr)*2048 + kh*1024 + lsw); }

#define RDKV_B(BUF) { \
    _Pragma("unroll") for (int fn = 0; fn < 4; fn++) \
    _Pragma("unroll") for (int kh = 0; kh < 2; kh++) \
        bfr[fn][kh] = *(const bf16x8*)(smB + (BUF)*16384 + (wn*4 + fn)*2048 + kh*1024 + lsw); }

#define MFMAKV(NHh) { \
    _Pragma("unroll") for (int kh = 0; kh < 2; kh++) \
    _Pragma("unroll") for (int fr = 0; fr < 4; fr++) \
    _Pragma("unroll") for (int fn = 0; fn < 2; fn++) \
        acc[fr][(NHh)*2+fn] = __builtin_amdgcn_mfma_f32_16x16x32_bf16( \
            af[fr][kh], bfr[(NHh)*2+fn][kh], acc[fr][(NHh)*2+fn], 0, 0, 0); }

#define STG_B128(KT, BUF) { \
    const unsigned short* _s = Bg + (size_t)(w*16 + srow)*K + (KT)*64 + scol; \
    char* _d = smB + (BUF)*16384 + w*2048; \
    gload_lds16(_s, _d); gload_lds16(_s + 32, _d + 1024); }

template<int OUT_BF16>
__global__ __launch_bounds__(512, 2) void gemm256x128_bt(const unsigned short* __restrict__ A,
                                                         const unsigned short* __restrict__ Bt,
                                                         const float* __restrict__ bias,
                                                         const float* __restrict__ bias2,
                                                         int nb1,
                                                         void* __restrict__ C, int ldc, int K){
    extern __shared__ char smem[];
    char* smA = smem;            // 2 x 32 KiB
    char* smB = smem + 65536;    // 2 x 16 KiB

    const int tid = threadIdx.x;
    const int lane = tid & 63, w = tid >> 6;          // 8 waves
    const int wm = w >> 1, wn = w & 1;                // 4M x 2N
    const int quad = lane >> 4, l16 = lane & 15;
    const int bm = blockIdx.x, bn = blockIdx.y;

    const int sl   = (lane & 32) ? (lane ^ 2) : lane;
    const int srow = sl >> 2;
    const int scol = (sl & 3) * 8;
    const int lsw  = l16*64 + ((quad*16) ^ ((l16 & 8) << 2));

    const unsigned short* Ag = A  + (size_t)(bm*256) * K;
    const unsigned short* Bg = Bt + (size_t)(bn*128) * K;

    f32x4 acc[4][4] = {};
    bf16x8 af[4][2], bfr[4][2];

    const int T = K >> 6;
    const int half = T >> 1;

    // prologue: tile0 (A+B) -> buf0 ; tile1 B -> buf1
    STG_A(0, 0, 0); STG_A(0, 1, 0); STG_B128(0, 0);
    STG_B128(1, 1);
    asm volatile("s_waitcnt vmcnt(2)" ::: "memory");   // tile0 landed; tile1-B in flight
    __builtin_amdgcn_s_barrier();
    asm volatile("" ::: "memory");

    for (int i = 0; i < half; ++i){
        const int t0 = 2*i;
        const bool pre = (i < half - 1);
        // ---- K-tile t0 from buf0 ----
        // P1: read all b0 frags; stage A(t0+1)->b1
        RDKV_A(0); RDKV_B(0);
        STG_A(t0+1, 0, 1); STG_A(t0+1, 1, 1);
        PH_MID(); MFMAKV(0); PH_END();
        // P2: stage next-pair tile into b0 (region free: b0 read only in P1)
        if (pre){ STG_A(t0+2, 0, 0); STG_A(t0+2, 1, 0); STG_B128(t0+2, 0); }
        PH_MID(); MFMAKV(1);
        if (pre) { PH_END_VM(6); } else { PH_END_VM(0); }   // tile t0+1 fully landed
        // ---- K-tile t0+1 from buf1 ----
        // P3: read all b1 frags
        RDKV_A(1); RDKV_B(1);
        PH_MID(); MFMAKV(0); PH_END();
        // P4: stage B(t0+3)->b1 (b1-B read drained at P3-mid)
        if (pre) STG_B128(t0+3, 1);
        PH_MID(); MFMAKV(1);
        if (pre) { PH_END_VM(2); }                          // tile t0+2 fully landed
        else     { __builtin_amdgcn_s_setprio(0); }
    }

    // epilogue (nf innermost for write-combining)
    float bb[4];
    #pragma unroll
    for (int fn = 0; fn < 4; fn++){
        int col = bn*128 + wn*64 + fn*16 + l16;
        bb[fn] = (col < nb1) ? bias[col] : bias2[col - nb1];
    }
    const size_t cb = (size_t)(bn*128 + wn*64);
    #pragma unroll
    for (int fr = 0; fr < 4; fr++){
        int row0 = bm*256 + wm*64 + fr*16 + quad*4;
        #pragma unroll
        for (int r = 0; r < 4; r++){
            size_t rb = (size_t)(row0+r)*ldc + cb;
            #pragma unroll
            for (int fn = 0; fn < 4; fn++){
                float v = acc[fr][fn][r] + bb[fn];
                if (OUT_BF16) ((unsigned short*)C)[rb + fn*16 + l16] = f2bf(v);
                else          ((float*)C)[rb + fn*16 + l16] = v;
            }
        }
    }
}

// ---------------- RoPE in-place on bf16, generic row stride ----------------
__global__ void rope_kernel(unsigned short* __restrict__ x, const float* __restrict__ cosp,
                            const float* __restrict__ sinp, int nheads, int rowstride,
                            float outscale, int total){
    int i = blockIdx.x * blockDim.x + threadIdx.x;
    if (i >= total) return;
    int d   = i & 63;
    int h   = (i >> 6) % nheads;
    int row = i / (64 * nheads);
    int s   = row & (SEQ - 1);
    size_t base = (size_t)row * rowstride + h * HD;
    float x1 = bf2f(x[base + d]), x2 = bf2f(x[base + d + 64]);
    float c1 = cosp[s*HD + d],  c2 = cosp[s*HD + d + 64];
    float s1 = sinp[s*HD + d],  s2 = sinp[s*HD + d + 64];
    x[base + d]      = f2bf((x1 * c1 - x2 * s1) * outscale);
    x[base + d + 64] = f2bf((x2 * c2 + x1 * s2) * outscale);
}

// ---------------- MFMA flash attention, balanced + drain-free pipeline ----------------
// grid (8 pairs, 28 heads, 2 batch), 256 threads = 4 waves.
// Block p processes qt = 15-p then qt = p  -> exactly 34 K-iters per block.
// Ks[2]: double-buffered; Vs single; Ps XOR-swizzled. T5 setprio around
// both MFMA clusters (attn blocks are NOT barrier-lockstep across the CU:
// 2 independent blocks/CU -> scheduler has waves to arbitrate).
__global__ __launch_bounds__(256, 2) void attn_mfma(const unsigned short* __restrict__ qkv,
                                                    const unsigned short* __restrict__ vt,
                                                    unsigned short* __restrict__ ao){
    __shared__ unsigned short Ks[2][16*64*8];
    __shared__ unsigned short Vs[8*128*8];
    __shared__ unsigned short Ps[128*64];
    const int h = blockIdx.y, b = blockIdx.z;
    const int g = h / NREP;
    const int tid = threadIdx.x;
    const int lane = tid & 63, w = tid >> 6;
    const int quad = lane >> 4, l16 = lane & 15;

    // DMA source bases (lane-fixed parts)
    const unsigned short* kdma  = qkv + (size_t)(b*SEQ + lane)*QKVN + 3584 + g*HD;
    const unsigned short* vdma0 = vt  + ((size_t)(b*NKV + g)*HD + lane)*SEQ;

    for (int ph = 0; ph < 2; ph++){
        const int qt = ph ? (int)blockIdx.x : (15 - (int)blockIdx.x);
        const int qrow0 = qt*128 + w*32;

        // Q fragments (A-layout, scale pre-folded by RoPE)
        bf16x8 qf[2][4];
        #pragma unroll
        for (int tm = 0; tm < 2; tm++){
            const unsigned short* qp = qkv + (size_t)(b*SEQ + qrow0 + tm*16 + l16)*QKVN + h*HD;
            #pragma unroll
            for (int kc = 0; kc < 4; kc++)
                qf[tm][kc] = *(const bf16x8*)&qp[kc*32 + quad*8];
        }

        f32x4 oacc[2][8];
        float m_i[2][4], l_i[2][4];
        #pragma unroll
        for (int tm = 0; tm < 2; tm++){
            #pragma unroll
            for (int tn = 0; tn < 8; tn++) oacc[tm][tn] = (f32x4){0.f, 0.f, 0.f, 0.f};
            #pragma unroll
            for (int r = 0; r < 4; r++){ m_i[tm][r] = -1e30f; l_i[tm][r] = 0.f; }
        }

        const int ktmax = 2*qt + 1;
        // prologue: DMA K(0) -> Ks[0]
        #pragma unroll
        for (int i = 0; i < 4; i++){
            int kc = w*4 + i;
            gload_lds16(kdma + kc*8, &Ks[0][kc*64*8]);
        }
        __syncthreads();   // drain K0 (once per phase)

        int cur = 0;
        for (int kt = 0; kt <= ktmax; kt++){
            // issue next-iteration K DMA into the other buffer (freed by prev b2)
            if (kt < ktmax){
                const unsigned short* kp = kdma + (size_t)((kt+1)*64)*QKVN;
                #pragma unroll
                for (int i = 0; i < 4; i++){
                    int kc = w*4 + i;
                    gload_lds16(kp + kc*8, &Ks[cur^1][kc*64*8]);
                }
            }
            // V DMA for this kt (Vs freed by prev b2; consumed after b1 below)
            #pragma unroll
            for (int i = 0; i < 4; i++){
                int e = w*4 + i, kch = e >> 1, half = e & 1;
                gload_lds16(vdma0 + (size_t)(half*64)*SEQ + kt*64 + kch*8,
                            &Vs[(kch*128 + half*64)*8]);
            }

            // S = Q K^T from Ks[cur]
            f32x4 sacc[2][4];
            #pragma unroll
            for (int tm = 0; tm < 2; tm++)
                #pragma unroll
                for (int tn = 0; tn < 4; tn++) sacc[tm][tn] = (f32x4){0.f, 0.f, 0.f, 0.f};
            __builtin_amdgcn_s_setprio(1);
            #pragma unroll
            for (int kc = 0; kc < 4; kc++){
                bf16x8 kf[4];
                #pragma unroll
                for (int tn = 0; tn < 4; tn++)
                    kf[tn] = *(const bf16x8*)&Ks[cur][((kc*4 + quad)*64 + tn*16 + l16)*8];
                #pragma unroll
                for (int tm = 0; tm < 2; tm++)
                    #pragma unroll
                    for (int tn = 0; tn < 4; tn++)
                        sacc[tm][tn] = __builtin_amdgcn_mfma_f32_16x16x32_bf16(qf[tm][kc], kf[tn], sacc[tm][tn], 0, 0, 0);
            }
            __builtin_amdgcn_s_setprio(0);

            // online softmax (exp2 domain; scale pre-folded into Q)
            const int kbase = kt*64;
            const bool need_mask = (kbase + 63 > qrow0);   // wave-uniform
            #pragma unroll
            for (int tm = 0; tm < 2; tm++){
                #pragma unroll
                for (int r = 0; r < 4; r++){
                    float sv[4];
                    #pragma unroll
                    for (int tn = 0; tn < 4; tn++) sv[tn] = sacc[tm][tn][r];
                    if (need_mask){
                        int qrow = qrow0 + tm*16 + quad*4 + r;
                        #pragma unroll
                        for (int tn = 0; tn < 4; tn++)
                            if (kbase + tn*16 + l16 > qrow) sv[tn] = -1e9f;
                    }
                    float rm = fmaxf(fmaxf(sv[0], sv[1]), fmaxf(sv[2], sv[3]));
                    rm = fmaxf(rm, __shfl_xor(rm, 1));
                    rm = fmaxf(rm, __shfl_xor(rm, 2));
                    rm = fmaxf(rm, __shfl_xor(rm, 4));
                    rm = fmaxf(rm, __shfl_xor(rm, 8));
                    float newm = fmaxf(m_i[tm][r], rm);
                    float alpha = exp2f(m_i[tm][r] - newm);
                    m_i[tm][r] = newm;
                    float rs = 0.f;
                    int prow = (w*32 + tm*16 + quad*4 + r)*64;
                    #pragma unroll
                    for (int tn = 0; tn < 4; tn++){
                        float p = exp2f(sv[tn] - newm);
                        rs += p;
                        Ps[prow + ((tn ^ quad) << 4) + l16] = f2bf(p);
                    }
                    l_i[tm][r] = l_i[tm][r] * alpha + rs;   // lane-partial l (reduced at epilogue)
                    #pragma unroll
                    for (int tn = 0; tn < 8; tn++) oacc[tm][tn][r] *= alpha;
                }
            }
            __syncthreads();   // b1: V ready, K(kt+1) drained early

            // O += P V
            __builtin_amdgcn_s_setprio(1);
            #pragma unroll
            for (int ks = 0; ks < 2; ks++){
                bf16x8 pf[2];
                #pragma unroll
                for (int tm = 0; tm < 2; tm++){
                    int prow = (w*32 + tm*16 + l16)*64;
                    int sw = (((2*ks + (quad >> 1)) ^ (l16 >> 2)) << 4) + (quad & 1)*8;
                    pf[tm] = *(const bf16x8*)&Ps[prow + sw];
                }
                #pragma unroll
                for (int tn = 0; tn < 8; tn++){
                    bf16x8 vf = *(const bf16x8*)&Vs[((ks*4 + quad)*128 + tn*16 + l16)*8];
                    #pragma unroll
                    for (int tm = 0; tm < 2; tm++)
                        oacc[tm][tn] = __builtin_amdgcn_mfma_f32_16x16x32_bf16(pf[tm], vf, oacc[tm][tn], 0, 0, 0);
                }
            }
            __builtin_amdgcn_s_setprio(0);
            __syncthreads();   // b2: frees Vs & Ks[cur]
            cur ^= 1;
        }

        // epilogue: reduce lane-partial l across the row's 16 lanes, write ao
        #pragma unroll
        for (int tm = 0; tm < 2; tm++){
            #pragma unroll
            for (int r = 0; r < 4; r++){
                float lt = l_i[tm][r];
                lt += __shfl_xor(lt, 1);
                lt += __shfl_xor(lt, 2);
                lt += __shfl_xor(lt, 4);
                lt += __shfl_xor(lt, 8);
                float inv = 1.f / lt;
                size_t base = ((size_t)(b*SEQ + qrow0 + tm*16 + quad*4 + r)) * (NH*HD) + h*HD;
                #pragma unroll
                for (int tn = 0; tn < 8; tn++)
                    ao[base + tn*16 + l16] = f2bf(oacc[tm][tn][r] * inv);
            }
        }
    }
}

extern "C" void kernel_launch(void* const* d_in, const int* in_sizes, int n_in,
                              void* d_out, int out_size, void* d_ws, size_t ws_size,
                              hipStream_t stream){
    const float* hs   = (const float*)d_in[0];
    const float* cosp = (const float*)d_in[1];
    const float* sinp = (const float*)d_in[2];
    const float* Wq   = (const float*)d_in[3];
    const float* bq   = (const float*)d_in[4];
    const float* Wk   = (const float*)d_in[5];
    const float* bk   = (const float*)d_in[6];
    const float* Wv   = (const float*)d_in[7];
    const float* bv   = (const float*)d_in[8];
    const float* Wo   = (const float*)d_in[9];
    float* out = (float*)d_out;
    char* ws = (char*)d_ws;

    // one-time: allow big dynamic LDS on the GEMMs
    static bool once = [](){
        hipFuncSetAttribute(reinterpret_cast<const void*>(gemm256_bt<1>),
                            hipFuncAttributeMaxDynamicSharedMemorySize, 131072);
        hipFuncSetAttribute(reinterpret_cast<const void*>(gemm256_bt<0>),
                            hipFuncAttributeMaxDynamicSharedMemorySize, 131072);
        hipFuncSetAttribute(reinterpret_cast<const void*>(gemm256x128_bt<1>),
                            hipFuncAttributeMaxDynamicSharedMemorySize, 98304);
        return true;
    }();
    (void)once;

    // workspace layout (bytes)
    unsigned short* hsb  = (unsigned short*)(ws + 0);          // 4096x3584 bf16 = 29,360,128
    unsigned short* Wqt  = (unsigned short*)(ws + 29360128);   // 3584x3584 bf16 (Wq^T)
    unsigned short* Wkt  = (unsigned short*)(ws + 55050240);   //  512x3584 bf16 (contiguous after Wqt)
    unsigned short* Wvt  = (unsigned short*)(ws + 58720256);   //  512x3584 bf16 (contiguous after Wkt)
    unsigned short* qkvb = (unsigned short*)(ws + 62390272);   // 4096x4608 bf16 = 37,748,736
    unsigned short* ao   = hsb;                                // reuse: hsb consumed by QKV gemms
    unsigned short* Wot  = Wqt;                                // reuse: W^T block consumed by Q gemm
    unsigned short* vtb  = (unsigned short*)(ws + 55050240);   // reuse Wkt/Wvt: 2x512x2048 bf16

    int n4 = MTOK * HIDDEN / 4;
    cast_f32_bf16<<<(n4 + 255) / 256, 256, 0, stream>>>(hs, hsb, n4);
    transpose_cast<<<dim3(112, 112), dim3(32, 8), 0, stream>>>(Wq, Wqt, HIDDEN, NH*HD);
    transpose_cast<<<dim3(16, 112),  dim3(32, 8), 0, stream>>>(Wk, Wkt, HIDDEN, NKV*HD);
    transpose_cast<<<dim3(16, 112),  dim3(32, 8), 0, stream>>>(Wv, Wvt, HIDDEN, NKV*HD);

    // Q projection: 16x14 = 224 blocks -> single CU round (no tail round)
    gemm256_bt<1><<<dim3(16, 14), 512, 131072, stream>>>(hsb, Wqt, bq, 3584,
                                                         qkvb, QKVN, HIDDEN);
    // KV projection: 16x8 = 128 half-size blocks -> ~half round
    gemm256x128_bt<1><<<dim3(16, 8), 512, 98304, stream>>>(hsb, Wkt, bk, bv, 512,
                                                           qkvb + 3584, QKVN, HIDDEN);

    // RoPE: q gets softmax scale*log2(e) folded in; k plain
    rope_kernel<<<(MTOK*NH*64  + 255) / 256, 256, 0, stream>>>(qkvb,        cosp, sinp, NH,  QKVN, SCALE2, MTOK*NH*64);
    rope_kernel<<<(MTOK*NKV*64 + 255) / 256, 256, 0, stream>>>(qkvb + 3584, cosp, sinp, NKV, QKVN, 1.0f,   MTOK*NKV*64);

    // V columns -> vt (overwrites Wkt/Wvt region; QKV gemms already done)
    transpose_v<<<dim3(64, 16, 2), dim3(32, 8), 0, stream>>>(qkvb, vtb);

    transpose_cast<<<dim3(112, 112), dim3(32, 8), 0, stream>>>(Wo, Wot, NH*HD, HIDDEN);

    attn_mfma<<<dim3(8, 28, 2), 256, 0, stream>>>(qkvb, vtb, ao);

    // output projection: 16x14 = 224 blocks, fp32 out
    gemm256_bt<0><<<dim3(16, 14), 512, 131072, stream>>>(ao, Wot, nullptr, 0,
                                                         out, HIDDEN, NH*HD);
}

// Round 4
// 652.005 us; speedup vs baseline: 1.1600x; 1.0145x over previous
//
#include <hip/hip_runtime.h>

#define HIDDEN 3584
#define NH 28
#define NKV 4
#define HD 128
#define NREP 7
#define SEQ 2048
#define BATCH 2
#define MTOK (BATCH*SEQ)   // 4096
#define QKVN 4608          // 3584 + 512 + 512
#define SCALE2 0.12751744f // 128^-0.5 * log2(e), folded into Q at RoPE

typedef __bf16 bf16x8 __attribute__((ext_vector_type(8)));
typedef float  f32x4  __attribute__((ext_vector_type(4)));

__device__ __forceinline__ unsigned short f2bf(float f){
    unsigned u = __builtin_bit_cast(unsigned, f);
    unsigned r = u + 0x7FFFu + ((u >> 16) & 1u);   // RNE
    return (unsigned short)(r >> 16);
}
__device__ __forceinline__ float bf2f(unsigned short h){
    unsigned u = ((unsigned)h) << 16;
    return __builtin_bit_cast(float, u);
}

// async global->LDS, 16B per lane; lds dest = wave-uniform base + lane*16
__device__ __forceinline__ void gload_lds16(const void* g, void* l){
    __builtin_amdgcn_global_load_lds(
        (const __attribute__((address_space(1))) void*)g,
        (__attribute__((address_space(3))) void*)l, 16, 0, 0);
}

// ---------------- elementwise cast fp32 -> bf16 ----------------
__global__ void cast_f32_bf16(const float* __restrict__ x, unsigned short* __restrict__ y, int n4){
    int i = blockIdx.x * blockDim.x + threadIdx.x;
    if (i < n4){
        float4 v = ((const float4*)x)[i];
        ushort4 o; o.x=f2bf(v.x); o.y=f2bf(v.y); o.z=f2bf(v.z); o.w=f2bf(v.w);
        ((ushort4*)y)[i] = o;
    }
}

// ---------------- W [K][N] fp32 -> Wt [N][K] bf16 ----------------
__global__ void transpose_cast(const float* __restrict__ W, unsigned short* __restrict__ Wt,
                               int K, int N){
    __shared__ float t[32][33];
    int n0 = blockIdx.x * 32, k0 = blockIdx.y * 32;
    int tx = threadIdx.x, ty = threadIdx.y;      // (32,8)
    #pragma unroll
    for (int r = 0; r < 4; r++)
        t[ty + r*8][tx] = W[(size_t)(k0 + ty + r*8) * N + n0 + tx];
    __syncthreads();
    #pragma unroll
    for (int r = 0; r < 4; r++)
        Wt[(size_t)(n0 + ty + r*8) * K + k0 + tx] = f2bf(t[tx][ty + r*8]);
}

// ---------------- V columns of qkv [B*S][4608] -> vt [B*512][SEQ] bf16 ----------------
__global__ void transpose_v(const unsigned short* __restrict__ qkv, unsigned short* __restrict__ vt){
    __shared__ unsigned short t[32][33];
    int s0 = blockIdx.x * 32, c0 = blockIdx.y * 32, b = blockIdx.z;
    int tx = threadIdx.x, ty = threadIdx.y;      // (32,8)
    #pragma unroll
    for (int r = 0; r < 4; r++)
        t[ty + r*8][tx] = qkv[(size_t)(b*SEQ + s0 + ty + r*8) * QKVN + 4096 + c0 + tx];
    __syncthreads();
    #pragma unroll
    for (int r = 0; r < 4; r++)
        vt[(size_t)(b*NKV*HD + c0 + ty + r*8) * SEQ + s0 + tx] = t[tx][ty + r*8];
}

// ======================================================================
// Shared pieces of the 8-phase GEMM family (m201-template port):
//   st_16x32 XOR swizzle; global_load_lds writes linearly -> swizzle via
//   inverse-permuted SOURCE lane (lane&32 ? lane^2 : lane) + swizzled
//   ds_read byte offset. Counted vmcnt (never 0 mid-loop).
// ======================================================================

#define STG_A(KT, H, BUF) { \
    const unsigned short* _s = Ag + (size_t)((H)*128 + w*16 + srow)*K + (KT)*64 + scol; \
    char* _d = smA + (BUF)*32768 + ((H)*8 + w)*2048; \
    gload_lds16(_s, _d); gload_lds16(_s + 32, _d + 1024); }

#define STG_B(KT, H, BUF) { \
    const unsigned short* _s = Bg + (size_t)((H)*128 + w*16 + srow)*K + (KT)*64 + scol; \
    char* _d = smB + (BUF)*32768 + ((H)*8 + w)*2048; \
    gload_lds16(_s, _d); gload_lds16(_s + 32, _d + 1024); }

// barrier -> drain LDS reads -> pin -> boost prio (MFMA cluster follows)
#define PH_MID() \
    asm volatile("" ::: "memory"); \
    __builtin_amdgcn_s_barrier(); \
    asm volatile("s_waitcnt lgkmcnt(0)" ::: "memory"); \
    __builtin_amdgcn_sched_barrier(0); \
    __builtin_amdgcn_s_setprio(1)

#define PH_END() \
    __builtin_amdgcn_s_setprio(0); \
    asm volatile("" ::: "memory"); \
    __builtin_amdgcn_s_barrier(); \
    asm volatile("" ::: "memory")

#define PH_END_VM(NN) \
    __builtin_amdgcn_s_setprio(0); \
    asm volatile("s_waitcnt vmcnt(" #NN ")" ::: "memory"); \
    __builtin_amdgcn_s_barrier(); \
    asm volatile("" ::: "memory")

// ======================================================================
// 256x256 8-phase GEMM: BM=BN=256, BK=64, 512 thr = 8 waves (2Mx4N),
// per-wave C = 128x64. LDS 128 KiB.
//   Stage ledger (iter i, tiles t0=2i in buf0, t0+1 in buf1):
//     P1:A0(t0+1)->b1  P2:A1(t0+1)->b1  P3:B0(t0+2)->b0  P4:B1(t0+2)->b0
//     P5:A0(t0+2)->b0  P6:A1(t0+2)->b0  P7:B0(t0+3)->b1  P8:B1(t0+3)->b1
//   vmcnt(4) at end-P4/P8 only; vmcnt(0) only last iteration.
// ======================================================================

#define RD_A(MH, BUF) { \
    _Pragma("unroll") for (int fr = 0; fr < 4; fr++) \
    _Pragma("unroll") for (int kh = 0; kh < 2; kh++) \
        af[fr][kh] = *(const bf16x8*)(smA + (BUF)*32768 + (wm*8 + (MH)*4 + fr)*2048 + kh*1024 + lsw); }

#define RD_B(DST, NHh, BUF) { \
    _Pragma("unroll") for (int fn = 0; fn < 2; fn++) \
    _Pragma("unroll") for (int kh = 0; kh < 2; kh++) \
        DST[fn][kh] = *(const bf16x8*)(smB + (BUF)*32768 + (wn*4 + (NHh)*2 + fn)*2048 + kh*1024 + lsw); }

#define MFMA_Q(MH, NHh, BF) { \
    _Pragma("unroll") for (int kh = 0; kh < 2; kh++) \
    _Pragma("unroll") for (int fr = 0; fr < 4; fr++) \
    _Pragma("unroll") for (int fn = 0; fn < 2; fn++) \
        acc[(MH)*4+fr][(NHh)*2+fn] = __builtin_amdgcn_mfma_f32_16x16x32_bf16( \
            af[fr][kh], BF[fn][kh], acc[(MH)*4+fr][(NHh)*2+fn], 0, 0, 0); }

template<int OUT_BF16>
__global__ __launch_bounds__(512, 2) void gemm256_bt(const unsigned short* __restrict__ A,
                                                     const unsigned short* __restrict__ Bt,
                                                     const float* __restrict__ bias,
                                                     int nb1,
                                                     void* __restrict__ C, int ldc, int K){
    extern __shared__ char smem[];
    char* smA = smem;            // 2 x 32 KiB
    char* smB = smem + 65536;    // 2 x 32 KiB

    const int tid = threadIdx.x;
    const int lane = tid & 63, w = tid >> 6;          // 8 waves
    const int wm = w >> 2, wn = w & 3;                // 2M x 4N
    const int quad = lane >> 4, l16 = lane & 15;
    const int bm = blockIdx.x, bn = blockIdx.y;

    // stage source-lane permutation (inverse of st_16x32 swizzle, rule #21)
    const int sl   = (lane & 32) ? (lane ^ 2) : lane;
    const int srow = sl >> 2;          // row within 16-row subtile
    const int scol = (sl & 3) * 8;     // col (elems) within 32-col group
    // swizzled per-lane ds_read byte offset within a 1024B subtile
    const int lsw  = l16*64 + ((quad*16) ^ ((l16 & 8) << 2));

    const unsigned short* Ag = A  + (size_t)(bm*256) * K;
    const unsigned short* Bg = Bt + (size_t)(bn*256) * K;

    f32x4 acc[8][4] = {};
    bf16x8 af[4][2], bf0[2][2], bf1[2][2];

    const int T = K >> 6;        // K-tiles
    const int half = T >> 1;

    // prologue: tile0 (all 4 halves) -> buf0 ; tile1 B-halves -> buf1
    STG_A(0, 0, 0); STG_A(0, 1, 0); STG_B(0, 0, 0); STG_B(0, 1, 0);
    STG_B(1, 0, 1); STG_B(1, 1, 1);
    asm volatile("s_waitcnt vmcnt(4)" ::: "memory");   // tile0 landed; tile1-B in flight
    __builtin_amdgcn_s_barrier();
    asm volatile("" ::: "memory");

    for (int i = 0; i < half; ++i){
        const int t0 = 2*i;
        const bool pre = (i < half - 1);
        // ---- K-tile t0 from buf0 ----
        // P1
        RD_A(0, 0); RD_B(bf0, 0, 0);
        STG_A(t0+1, 0, 1);
        PH_MID(); MFMA_Q(0, 0, bf0); PH_END();
        // P2
        RD_B(bf1, 1, 0);
        STG_A(t0+1, 1, 1);
        PH_MID(); MFMA_Q(0, 1, bf1); PH_END();
        // P3
        RD_A(1, 0);
        if (pre) STG_B(t0+2, 0, 0);
        PH_MID(); MFMA_Q(1, 1, bf1); PH_END();
        // P4 (no reads; af=mh1 from P3, bf0 from P1)
        if (pre) STG_B(t0+2, 1, 0);
        PH_MID(); MFMA_Q(1, 0, bf0);
        if (pre) { PH_END_VM(4); } else { PH_END_VM(0); }   // tile t0+1 fully landed
        // ---- K-tile t0+1 from buf1 ----
        // P5
        RD_A(0, 1); RD_B(bf0, 0, 1);
        if (pre) STG_A(t0+2, 0, 0);
        PH_MID(); MFMA_Q(0, 0, bf0); PH_END();
        // P6
        RD_B(bf1, 1, 1);
        if (pre) STG_A(t0+2, 1, 0);
        PH_MID(); MFMA_Q(0, 1, bf1); PH_END();
        // P7
        RD_A(1, 1);
        if (pre) STG_B(t0+3, 0, 1);
        PH_MID(); MFMA_Q(1, 1, bf1); PH_END();
        // P8
        if (pre) STG_B(t0+3, 1, 1);
        PH_MID(); MFMA_Q(1, 0, bf0);
        if (pre) { PH_END_VM(4); }                           // tile t0+2 fully landed
        else     { __builtin_amdgcn_s_setprio(0); }          // last iter: nothing outstanding
    }

    // epilogue: nf innermost so the four 32B chunks of each 128B row-segment
    // are written back-to-back (write-combine; kills the RMW amplification)
    float bb[4];
    #pragma unroll
    for (int nf = 0; nf < 4; nf++){
        int col = bn*256 + wn*64 + nf*16 + l16;
        bb[nf] = (bias && col < nb1) ? bias[col] : 0.f;
    }
    const size_t cb = (size_t)(bn*256 + wn*64);
    #pragma unroll
    for (int mf = 0; mf < 8; mf++){
        int row0 = bm*256 + wm*128 + mf*16 + quad*4;
        #pragma unroll
        for (int r = 0; r < 4; r++){
            size_t rb = (size_t)(row0+r)*ldc + cb;
            #pragma unroll
            for (int nf = 0; nf < 4; nf++){
                float v = acc[mf][nf][r] + bb[nf];
                if (OUT_BF16) ((unsigned short*)C)[rb + nf*16 + l16] = f2bf(v);
                else          ((float*)C)[rb + nf*16 + l16] = v;
            }
        }
    }
}

// ======================================================================
// 256x128 4-phase GEMM (KV projection): BM=256, BN=128, BK=64,
// 512 thr = 8 waves (4M x 2N), per-wave C = 64x64. LDS 96 KiB
// (A 2x32K + B 2x16K). 4 phases / 2 K-tiles per iter.
//   P1: A(t0+1)->b1   P2: A(t0+2)+B(t0+2)->b0   P3: -   P4: B(t0+3)->b1
//   Waits: end-P2 vmcnt(6), end-P4 vmcnt(2).
// ======================================================================

#define RDKV_A(BUF) { \
    _Pragma("unroll") for (int fr = 0; fr < 4; fr++) \
    _Pragma("unroll") for (int kh = 0; kh < 2; kh++) \
        af[fr][kh] = *(const bf16x8*)(smA + (BUF)*32768 + (wm*4 + fr)*2048 + kh*1024 + lsw); }

#define RDKV_B(BUF) { \
    _Pragma("unroll") for (int fn = 0; fn < 4; fn++) \
    _Pragma("unroll") for (int kh = 0; kh < 2; kh++) \
        bfr[fn][kh] = *(const bf16x8*)(smB + (BUF)*16384 + (wn*4 + fn)*2048 + kh*1024 + lsw); }

#define MFMAKV(NHh) { \
    _Pragma("unroll") for (int kh = 0; kh < 2; kh++) \
    _Pragma("unroll") for (int fr = 0; fr < 4; fr++) \
    _Pragma("unroll") for (int fn = 0; fn < 2; fn++) \
        acc[fr][(NHh)*2+fn] = __builtin_amdgcn_mfma_f32_16x16x32_bf16( \
            af[fr][kh], bfr[(NHh)*2+fn][kh], acc[fr][(NHh)*2+fn], 0, 0, 0); }

#define STG_B128(KT, BUF) { \
    const unsigned short* _s = Bg + (size_t)(w*16 + srow)*K + (KT)*64 + scol; \
    char* _d = smB + (BUF)*16384 + w*2048; \
    gload_lds16(_s, _d); gload_lds16(_s + 32, _d + 1024); }

template<int OUT_BF16>
__global__ __launch_bounds__(512, 2) void gemm256x128_bt(const unsigned short* __restrict__ A,
                                                         const unsigned short* __restrict__ Bt,
                                                         const float* __restrict__ bias,
                                                         const float* __restrict__ bias2,
                                                         int nb1,
                                                         void* __restrict__ C, int ldc, int K){
    extern __shared__ char smem[];
    char* smA = smem;            // 2 x 32 KiB
    char* smB = smem + 65536;    // 2 x 16 KiB

    const int tid = threadIdx.x;
    const int lane = tid & 63, w = tid >> 6;          // 8 waves
    const int wm = w >> 1, wn = w & 1;                // 4M x 2N
    const int quad = lane >> 4, l16 = lane & 15;
    const int bm = blockIdx.x, bn = blockIdx.y;

    const int sl   = (lane & 32) ? (lane ^ 2) : lane;
    const int srow = sl >> 2;
    const int scol = (sl & 3) * 8;
    const int lsw  = l16*64 + ((quad*16) ^ ((l16 & 8) << 2));

    const unsigned short* Ag = A  + (size_t)(bm*256) * K;
    const unsigned short* Bg = Bt + (size_t)(bn*128) * K;

    f32x4 acc[4][4] = {};
    bf16x8 af[4][2], bfr[4][2];

    const int T = K >> 6;
    const int half = T >> 1;

    // prologue: tile0 (A+B) -> buf0 ; tile1 B -> buf1
    STG_A(0, 0, 0); STG_A(0, 1, 0); STG_B128(0, 0);
    STG_B128(1, 1);
    asm volatile("s_waitcnt vmcnt(2)" ::: "memory");   // tile0 landed; tile1-B in flight
    __builtin_amdgcn_s_barrier();
    asm volatile("" ::: "memory");

    for (int i = 0; i < half; ++i){
        const int t0 = 2*i;
        const bool pre = (i < half - 1);
        // P1: read all b0 frags; stage A(t0+1)->b1
        RDKV_A(0); RDKV_B(0);
        STG_A(t0+1, 0, 1); STG_A(t0+1, 1, 1);
        PH_MID(); MFMAKV(0); PH_END();
        // P2: stage next-pair tile into b0 (region free: b0 read only in P1)
        if (pre){ STG_A(t0+2, 0, 0); STG_A(t0+2, 1, 0); STG_B128(t0+2, 0); }
        PH_MID(); MFMAKV(1);
        if (pre) { PH_END_VM(6); } else { PH_END_VM(0); }   // tile t0+1 fully landed
        // P3: read all b1 frags
        RDKV_A(1); RDKV_B(1);
        PH_MID(); MFMAKV(0); PH_END();
        // P4: stage B(t0+3)->b1 (b1-B read drained at P3-mid)
        if (pre) STG_B128(t0+3, 1);
        PH_MID(); MFMAKV(1);
        if (pre) { PH_END_VM(2); }                          // tile t0+2 fully landed
        else     { __builtin_amdgcn_s_setprio(0); }
    }

    // epilogue (nf innermost for write-combining)
    float bb[4];
    #pragma unroll
    for (int fn = 0; fn < 4; fn++){
        int col = bn*128 + wn*64 + fn*16 + l16;
        bb[fn] = (col < nb1) ? bias[col] : bias2[col - nb1];
    }
    const size_t cb = (size_t)(bn*128 + wn*64);
    #pragma unroll
    for (int fr = 0; fr < 4; fr++){
        int row0 = bm*256 + wm*64 + fr*16 + quad*4;
        #pragma unroll
        for (int r = 0; r < 4; r++){
            size_t rb = (size_t)(row0+r)*ldc + cb;
            #pragma unroll
            for (int fn = 0; fn < 4; fn++){
                float v = acc[fr][fn][r] + bb[fn];
                if (OUT_BF16) ((unsigned short*)C)[rb + fn*16 + l16] = f2bf(v);
                else          ((float*)C)[rb + fn*16 + l16] = v;
            }
        }
    }
}

// ---------------- RoPE in-place on bf16, generic row stride ----------------
__global__ void rope_kernel(unsigned short* __restrict__ x, const float* __restrict__ cosp,
                            const float* __restrict__ sinp, int nheads, int rowstride,
                            float outscale, int total){
    int i = blockIdx.x * blockDim.x + threadIdx.x;
    if (i >= total) return;
    int d   = i & 63;
    int h   = (i >> 6) % nheads;
    int row = i / (64 * nheads);
    int s   = row & (SEQ - 1);
    size_t base = (size_t)row * rowstride + h * HD;
    float x1 = bf2f(x[base + d]), x2 = bf2f(x[base + d + 64]);
    float c1 = cosp[s*HD + d],  c2 = cosp[s*HD + d + 64];
    float s1 = sinp[s*HD + d],  s2 = sinp[s*HD + d + 64];
    x[base + d]      = f2bf((x1 * c1 - x2 * s1) * outscale);
    x[base + d + 64] = f2bf((x2 * c2 + x1 * s2) * outscale);
}

// ---------------- MFMA flash attention, coalesced swizzled DMA ----------------
// grid (8 pairs, 28 heads, 2 batch), 256 threads = 4 waves.
// Block p processes qt = 15-p then qt = p  -> 36 K-iters per block.
// Ks[2][64][128]: [key][d] 256B rows, double-buffered, byte^=((key&7)<<4)
//   swizzle applied via inverse-XOR'd SOURCE offset (linear LDS dest) and
//   XOR'd ds_read fragment addr -> coalesced 256B-row DMA + 2-way-free reads.
// Vs[128][64]: [d][key] 128B rows, byte^=((d&7)<<4), same recipe, from vt.
// Per iter: issue V(kt) FIRST then K(kt+1); b1 = vmcnt(4) (drains V only,
// K(kt+1) rides through PV) + lgkmcnt(0) (Ps visible); b2 = vmcnt(0)
// (K landed; had softmax+PV to cover) -> never a cold drain.
__global__ __launch_bounds__(256, 2) void attn_mfma(const unsigned short* __restrict__ qkv,
                                                    const unsigned short* __restrict__ vt,
                                                    unsigned short* __restrict__ ao){
    __shared__ unsigned short Ks[2][64*128];
    __shared__ unsigned short Vs[128*64];
    __shared__ unsigned short Ps[128*64];
    const int h = blockIdx.y, b = blockIdx.z;
    const int g = h / NREP;
    const int tid = threadIdx.x;
    const int lane = tid & 63, w = tid >> 6;
    const int quad = lane >> 4, l16 = lane & 15;

    // K staging precompute: gload gg covers keys 4gg..4gg+3 (256B rows).
    // lane: key sub-row kl=lane>>4, dest byte (lane&15)*16; source offset
    // pre-XOR'd by ((key&7)<<4) so linear dest holds the swizzled layout.
    const int kl  = lane >> 4;
    const int kds = (lane & 15) << 4;
    const int koe = (kds ^ (kl << 4)) >> 1;          // elems, even gg (key&7 = kl)
    const int koo = (kds ^ ((4 + kl) << 4)) >> 1;    // elems, odd gg (key&7 = 4+kl)
    const unsigned short* kbase = qkv + (size_t)(b*SEQ + kl)*QKVN + 3584 + g*HD;
    // V staging precompute: gload gg covers d-rows 8gg..8gg+7 (128B segs of vt).
    const int vrow = lane >> 3;
    const int voff = ((((lane & 7) << 4)) ^ (vrow << 4)) >> 1;
    const unsigned short* vbase = vt + ((size_t)(b*NKV + g)*HD + vrow)*SEQ + voff;
    // read-side XOR (element units: byte ((l16&7)<<4) -> elem (l16&7)*8)
    const int kxe = (l16 & 7) * 8;

    for (int ph = 0; ph < 2; ph++){
        const int qt = ph ? (int)blockIdx.x : (15 - (int)blockIdx.x);
        const int qrow0 = qt*128 + w*32;

        // Q fragments (A-layout, scale pre-folded by RoPE)
        bf16x8 qf[2][4];
        #pragma unroll
        for (int tm = 0; tm < 2; tm++){
            const unsigned short* qp = qkv + (size_t)(b*SEQ + qrow0 + tm*16 + l16)*QKVN + h*HD;
            #pragma unroll
            for (int kc = 0; kc < 4; kc++)
                qf[tm][kc] = *(const bf16x8*)&qp[kc*32 + quad*8];
        }

        f32x4 oacc[2][8];
        float m_i[2][4], l_i[2][4];
        #pragma unroll
        for (int tm = 0; tm < 2; tm++){
            #pragma unroll
            for (int tn = 0; tn < 8; tn++) oacc[tm][tn] = (f32x4){0.f, 0.f, 0.f, 0.f};
            #pragma unroll
            for (int r = 0; r < 4; r++){ m_i[tm][r] = -1e30f; l_i[tm][r] = 0.f; }
        }

        const int ktmax = 2*qt + 1;
        // prologue: K(0) -> Ks[0] (coalesced rows)
        #pragma unroll
        for (int i = 0; i < 4; i++){
            int gg = w*4 + i;
            gload_lds16(kbase + (size_t)(4*gg)*QKVN + ((gg & 1) ? koo : koe),
                        &Ks[0][gg*512]);
        }
        __syncthreads();   // drain K0 (once per phase)

        int cur = 0;
        for (int kt = 0; kt <= ktmax; kt++){
            // V(kt) first (drained at b1) ...
            #pragma unroll
            for (int i = 0; i < 4; i++){
                int gg = w*4 + i;
                gload_lds16(vbase + (size_t)(8*gg)*SEQ + kt*64, &Vs[gg*512]);
            }
            // ... then K(kt+1) into the other buffer (rides through PV)
            if (kt < ktmax){
                const unsigned short* kp = kbase + (size_t)((kt+1)*64)*QKVN;
                #pragma unroll
                for (int i = 0; i < 4; i++){
                    int gg = w*4 + i;
                    gload_lds16(kp + (size_t)(4*gg)*QKVN + ((gg & 1) ? koo : koe),
                                &Ks[cur^1][gg*512]);
                }
            }

            // S = Q K^T from Ks[cur]  (swizzled fragment reads, 2-way free)
            f32x4 sacc[2][4];
            #pragma unroll
            for (int tm = 0; tm < 2; tm++)
                #pragma unroll
                for (int tn = 0; tn < 4; tn++) sacc[tm][tn] = (f32x4){0.f, 0.f, 0.f, 0.f};
            __builtin_amdgcn_s_setprio(1);
            #pragma unroll
            for (int kc = 0; kc < 4; kc++){
                bf16x8 kf[4];
                #pragma unroll
                for (int tn = 0; tn < 4; tn++)
                    kf[tn] = *(const bf16x8*)&Ks[cur][(tn*16 + l16)*128 + (((kc*4 + quad)*8) ^ kxe)];
                #pragma unroll
                for (int tm = 0; tm < 2; tm++)
                    #pragma unroll
                    for (int tn = 0; tn < 4; tn++)
                        sacc[tm][tn] = __builtin_amdgcn_mfma_f32_16x16x32_bf16(qf[tm][kc], kf[tn], sacc[tm][tn], 0, 0, 0);
            }
            __builtin_amdgcn_s_setprio(0);

            // online softmax (exp2 domain; scale pre-folded into Q)
            const int kbase_i = kt*64;
            const bool need_mask = (kbase_i + 63 > qrow0);   // wave-uniform
            #pragma unroll
            for (int tm = 0; tm < 2; tm++){
                #pragma unroll
                for (int r = 0; r < 4; r++){
                    float sv[4];
                    #pragma unroll
                    for (int tn = 0; tn < 4; tn++) sv[tn] = sacc[tm][tn][r];
                    if (need_mask){
                        int qrow = qrow0 + tm*16 + quad*4 + r;
                        #pragma unroll
                        for (int tn = 0; tn < 4; tn++)
                            if (kbase_i + tn*16 + l16 > qrow) sv[tn] = -1e9f;
                    }
                    float rm = fmaxf(fmaxf(sv[0], sv[1]), fmaxf(sv[2], sv[3]));
                    rm = fmaxf(rm, __shfl_xor(rm, 1));
                    rm = fmaxf(rm, __shfl_xor(rm, 2));
                    rm = fmaxf(rm, __shfl_xor(rm, 4));
                    rm = fmaxf(rm, __shfl_xor(rm, 8));
                    float newm = fmaxf(m_i[tm][r], rm);
                    float alpha = exp2f(m_i[tm][r] - newm);
                    m_i[tm][r] = newm;
                    float rs = 0.f;
                    int prow = (w*32 + tm*16 + quad*4 + r)*64;
                    #pragma unroll
                    for (int tn = 0; tn < 4; tn++){
                        float p = exp2f(sv[tn] - newm);
                        rs += p;
                        Ps[prow + ((tn ^ quad) << 4) + l16] = f2bf(p);
                    }
                    l_i[tm][r] = l_i[tm][r] * alpha + rs;   // lane-partial l (reduced at epilogue)
                    #pragma unroll
                    for (int tn = 0; tn < 8; tn++) oacc[tm][tn][r] *= alpha;
                }
            }
            // b1: V landed (counted), Ps visible; K(kt+1) stays in flight
            if (kt < ktmax){ asm volatile("s_waitcnt vmcnt(4) lgkmcnt(0)" ::: "memory"); }
            else           { asm volatile("s_waitcnt vmcnt(0) lgkmcnt(0)" ::: "memory"); }
            __builtin_amdgcn_s_barrier();
            asm volatile("" ::: "memory");

            // O += P V : A-frags from swizzled Ps, B-frags from swizzled Vs
            __builtin_amdgcn_s_setprio(1);
            #pragma unroll
            for (int ks = 0; ks < 2; ks++){
                bf16x8 pf[2];
                #pragma unroll
                for (int tm = 0; tm < 2; tm++){
                    int prow = (w*32 + tm*16 + l16)*64;
                    int sw = (((2*ks + (quad >> 1)) ^ (l16 >> 2)) << 4) + (quad & 1)*8;
                    pf[tm] = *(const bf16x8*)&Ps[prow + sw];
                }
                #pragma unroll
                for (int tn = 0; tn < 8; tn++){
                    bf16x8 vf = *(const bf16x8*)&Vs[(tn*16 + l16)*64 + (((ks*4 + quad)*8) ^ kxe)];
                    #pragma unroll
                    for (int tm = 0; tm < 2; tm++)
                        oacc[tm][tn] = __builtin_amdgcn_mfma_f32_16x16x32_bf16(pf[tm], vf, oacc[tm][tn], 0, 0, 0);
                }
            }
            __builtin_amdgcn_s_setprio(0);
            // b2: drain K(kt+1) (issued ~softmax+PV ago -> near-free); frees Vs & Ks[cur]
            asm volatile("s_waitcnt vmcnt(0) lgkmcnt(0)" ::: "memory");
            __builtin_amdgcn_s_barrier();
            asm volatile("" ::: "memory");
            cur ^= 1;
        }

        // epilogue: reduce lane-partial l across the row's 16 lanes, write ao
        #pragma unroll
        for (int tm = 0; tm < 2; tm++){
            #pragma unroll
            for (int r = 0; r < 4; r++){
                float lt = l_i[tm][r];
                lt += __shfl_xor(lt, 1);
                lt += __shfl_xor(lt, 2);
                lt += __shfl_xor(lt, 4);
                lt += __shfl_xor(lt, 8);
                float inv = 1.f / lt;
                size_t base = ((size_t)(b*SEQ + qrow0 + tm*16 + quad*4 + r)) * (NH*HD) + h*HD;
                #pragma unroll
                for (int tn = 0; tn < 8; tn++)
                    ao[base + tn*16 + l16] = f2bf(oacc[tm][tn][r] * inv);
            }
        }
    }
}

extern "C" void kernel_launch(void* const* d_in, const int* in_sizes, int n_in,
                              void* d_out, int out_size, void* d_ws, size_t ws_size,
                              hipStream_t stream){
    const float* hs   = (const float*)d_in[0];
    const float* cosp = (const float*)d_in[1];
    const float* sinp = (const float*)d_in[2];
    const float* Wq   = (const float*)d_in[3];
    const float* bq   = (const float*)d_in[4];
    const float* Wk   = (const float*)d_in[5];
    const float* bk   = (const float*)d_in[6];
    const float* Wv   = (const float*)d_in[7];
    const float* bv   = (const float*)d_in[8];
    const float* Wo   = (const float*)d_in[9];
    float* out = (float*)d_out;
    char* ws = (char*)d_ws;

    // one-time: allow big dynamic LDS on the GEMMs
    static bool once = [](){
        hipFuncSetAttribute(reinterpret_cast<const void*>(gemm256_bt<1>),
                            hipFuncAttributeMaxDynamicSharedMemorySize, 131072);
        hipFuncSetAttribute(reinterpret_cast<const void*>(gemm256_bt<0>),
                            hipFuncAttributeMaxDynamicSharedMemorySize, 131072);
        hipFuncSetAttribute(reinterpret_cast<const void*>(gemm256x128_bt<1>),
                            hipFuncAttributeMaxDynamicSharedMemorySize, 98304);
        return true;
    }();
    (void)once;

    // workspace layout (bytes)
    unsigned short* hsb  = (unsigned short*)(ws + 0);          // 4096x3584 bf16 = 29,360,128
    unsigned short* Wqt  = (unsigned short*)(ws + 29360128);   // 3584x3584 bf16 (Wq^T)
    unsigned short* Wkt  = (unsigned short*)(ws + 55050240);   //  512x3584 bf16 (contiguous after Wqt)
    unsigned short* Wvt  = (unsigned short*)(ws + 58720256);   //  512x3584 bf16 (contiguous after Wkt)
    unsigned short* qkvb = (unsigned short*)(ws + 62390272);   // 4096x4608 bf16 = 37,748,736
    unsigned short* ao   = hsb;                                // reuse: hsb consumed by QKV gemms
    unsigned short* Wot  = Wqt;                                // reuse: W^T block consumed by Q gemm
    unsigned short* vtb  = (unsigned short*)(ws + 55050240);   // reuse Wkt/Wvt: 2x512x2048 bf16

    int n4 = MTOK * HIDDEN / 4;
    cast_f32_bf16<<<(n4 + 255) / 256, 256, 0, stream>>>(hs, hsb, n4);
    transpose_cast<<<dim3(112, 112), dim3(32, 8), 0, stream>>>(Wq, Wqt, HIDDEN, NH*HD);
    transpose_cast<<<dim3(16, 112),  dim3(32, 8), 0, stream>>>(Wk, Wkt, HIDDEN, NKV*HD);
    transpose_cast<<<dim3(16, 112),  dim3(32, 8), 0, stream>>>(Wv, Wvt, HIDDEN, NKV*HD);

    // Q projection: 16x14 = 224 blocks -> single CU round (no tail round)
    gemm256_bt<1><<<dim3(16, 14), 512, 131072, stream>>>(hsb, Wqt, bq, 3584,
                                                         qkvb, QKVN, HIDDEN);
    // KV projection: 16x8 = 128 half-size blocks -> ~half round
    gemm256x128_bt<1><<<dim3(16, 8), 512, 98304, stream>>>(hsb, Wkt, bk, bv, 512,
                                                           qkvb + 3584, QKVN, HIDDEN);

    // RoPE: q gets softmax scale*log2(e) folded in; k plain
    rope_kernel<<<(MTOK*NH*64  + 255) / 256, 256, 0, stream>>>(qkvb,        cosp, sinp, NH,  QKVN, SCALE2, MTOK*NH*64);
    rope_kernel<<<(MTOK*NKV*64 + 255) / 256, 256, 0, stream>>>(qkvb + 3584, cosp, sinp, NKV, QKVN, 1.0f,   MTOK*NKV*64);

    // V columns -> vt (overwrites Wkt/Wvt region; QKV gemms already done)
    transpose_v<<<dim3(64, 16, 2), dim3(32, 8), 0, stream>>>(qkvb, vtb);

    transpose_cast<<<dim3(112, 112), dim3(32, 8), 0, stream>>>(Wo, Wot, NH*HD, HIDDEN);

    attn_mfma<<<dim3(8, 28, 2), 256, 0, stream>>>(qkvb, vtb, ao);

    // output projection: 16x14 = 224 blocks, fp32 out
    gemm256_bt<0><<<dim3(16, 14), 512, 131072, stream>>>(ao, Wot, nullptr, 0,
                                                         out, HIDDEN, NH*HD);
}